// Round 1
// baseline (6803.537 us; speedup 1.0000x reference)
//
#include <hip/hip_runtime.h>
#include <math.h>

#define TPB 256

// ---------------------------------------------------------------------------
// Per-sample separable 1D gaussian kernels (normalized), all 3 levels at once.
// k1d layout: [lvl][b][9], lvl = column index into alphas (0->256^2, 1->128^2, 2->64^2)
// ---------------------------------------------------------------------------
__global__ __launch_bounds__(128) void gauss1d_kernel(const float* __restrict__ alphas,
                                                      float* __restrict__ k1d) {
  int t = threadIdx.x;
  if (t >= 108) return;
  int lvl = t / 36;
  int rem = t - lvl * 36;
  int b = rem / 9;
  int j = rem - b * 9;
  float alpha = alphas[b * 3 + lvl];
  float k = floorf(floorf(alpha * 8.f) * 0.5f) * 2.f + 1.f;
  float r = (k - 1.f) * 0.5f;
  float sum = 0.f, val = 0.f;
  for (int u = 0; u < 9; ++u) {
    float d = (float)(u - 4);
    float g = expf(-(d * d) / 512.f);   // 2*sigma^2 = 512
    if (fabsf(d) > r) g = 0.f;
    if (u == j) val = g;
    sum += g;
  }
  k1d[(lvl * 4 + b) * 9 + j] = val / sum;
}

// ---------------------------------------------------------------------------
// Per-(b,c) mean + unbiased std over HW. One block per (b,c).
// ---------------------------------------------------------------------------
__global__ __launch_bounds__(TPB) void stats_kernel(const float* __restrict__ x,
                                                    float* __restrict__ mean,
                                                    float* __restrict__ stdv, int HW) {
  long long base = (long long)blockIdx.x * HW;
  float s = 0.f, q = 0.f;
  for (int i = threadIdx.x; i < HW; i += TPB) {
    float v = x[base + i];
    s += v;
    q = fmaf(v, v, q);
  }
#pragma unroll
  for (int off = 32; off > 0; off >>= 1) {
    s += __shfl_down(s, off, 64);
    q += __shfl_down(q, off, 64);
  }
  __shared__ float sm[8];
  int w = threadIdx.x >> 6, lane = threadIdx.x & 63;
  if (lane == 0) { sm[w * 2] = s; sm[w * 2 + 1] = q; }
  __syncthreads();
  if (threadIdx.x == 0) {
    float S = sm[0] + sm[2] + sm[4] + sm[6];
    float Q = sm[1] + sm[3] + sm[5] + sm[7];
    float m = S / (float)HW;
    float var = (Q - S * m) / (float)(HW - 1);
    mean[blockIdx.x] = m;
    stdv[blockIdx.x] = sqrtf(fmaxf(var, 0.f));
  }
}

// ---------------------------------------------------------------------------
// 2x2 mean pool: dst has half resolution. n = total dst elements.
// ---------------------------------------------------------------------------
__global__ __launch_bounds__(TPB) void pool2_kernel(const float* __restrict__ src,
                                                    float* __restrict__ dst,
                                                    int lwh, int lhh, long long n) {
  long long i = (long long)blockIdx.x * TPB + threadIdx.x;
  if (i >= n) return;
  int Wh = 1 << lwh, Hh = 1 << lhh;
  int px = (int)(i & (Wh - 1));
  int py = (int)((i >> lwh) & (Hh - 1));
  long long bc = i >> (lwh + lhh);
  const float* sp = src + (bc << (lwh + lhh + 2)) + (long long)(py * 2) * (Wh * 2) + px * 2;
  dst[i] = 0.25f * (sp[0] + sp[1] + sp[Wh * 2] + sp[Wh * 2 + 1]);
}

// ---------------------------------------------------------------------------
// Nearest 2x upsample. lw/lh are log2 of OUTPUT dims. n = total dst elements.
// ---------------------------------------------------------------------------
__global__ __launch_bounds__(TPB) void up2_kernel(const float* __restrict__ src,
                                                  float* __restrict__ dst,
                                                  int lw, int lh, long long n) {
  long long i = (long long)blockIdx.x * TPB + threadIdx.x;
  if (i >= n) return;
  int Wo = 1 << lw, Ho = 1 << lh;
  int x = (int)(i & (Wo - 1));
  int y = (int)((i >> lw) & (Ho - 1));
  long long bc = i >> (lw + lh);
  dst[i] = src[(bc << (lw + lh - 2)) + (long long)(y >> 1) * (Wo >> 1) + (x >> 1)];
}

// ---------------------------------------------------------------------------
// blurX: dst = 1D conv over x (replicate pad) of hh(c) where
//        hh(y,x) = c[y][x] - pool[y>>1][x>>1]  (pool precomputed)
// ---------------------------------------------------------------------------
__global__ __launch_bounds__(TPB) void blurx_kernel(const float* __restrict__ src,
                                                    const float* __restrict__ pmap,
                                                    const float* __restrict__ k1d,
                                                    float* __restrict__ dst,
                                                    int C, int lw, int lh) {
  int b = blockIdx.z;
  float kb[9];
#pragma unroll
  for (int t = 0; t < 9; ++t) kb[t] = k1d[b * 9 + t];
  int W = 1 << lw, H = 1 << lh;
  (void)H;
  long long i = (long long)blockIdx.x * TPB + threadIdx.x;
  long long nper = (long long)C << (lw + lh);
  if (i >= nper) return;
  int x = (int)(i & (W - 1));
  long long rest = i >> lw;
  int y = (int)(rest & ((1 << lh) - 1));
  int c = (int)(rest >> lh);
  long long bc = (long long)b * C + c;
  const float* sp = src + (bc << (lw + lh)) + ((long long)y << lw);
  const float* pp = pmap + (bc << (lw + lh - 2)) + ((long long)(y >> 1) << (lw - 1));
  float s = 0.f;
#pragma unroll
  for (int t = 0; t < 9; ++t) {
    int px = x + t - 4;
    px = px < 0 ? 0 : (px > W - 1 ? W - 1 : px);
    s = fmaf(kb[t], sp[px] - pp[px >> 1], s);
  }
  dst[(bc << (lw + lh)) + ((long long)y << lw) + x] = s;
}

// ---------------------------------------------------------------------------
// blurY + scale + add:  out += (std_s/(std_c+eps)) * 1D conv over y of tmp
// ---------------------------------------------------------------------------
__global__ __launch_bounds__(TPB) void blury_add_kernel(const float* __restrict__ tmp,
                                                        float* __restrict__ out,
                                                        const float* __restrict__ k1d,
                                                        const float* __restrict__ stdc,
                                                        const float* __restrict__ stds,
                                                        int C, int lw, int lh) {
  int b = blockIdx.z;
  float kb[9];
#pragma unroll
  for (int t = 0; t < 9; ++t) kb[t] = k1d[b * 9 + t];
  int W = 1 << lw, H = 1 << lh;
  long long i = (long long)blockIdx.x * TPB + threadIdx.x;
  long long nper = (long long)C << (lw + lh);
  if (i >= nper) return;
  int x = (int)(i & (W - 1));
  long long rest = i >> lw;
  int y = (int)(rest & (H - 1));
  int c = (int)(rest >> lh);
  int bc = b * C + c;
  float a = stds[bc] / (stdc[bc] + 1e-5f);
  const float* tp = tmp + ((long long)bc << (lw + lh)) + x;
  float s = 0.f;
#pragma unroll
  for (int t = 0; t < 9; ++t) {
    int py = y + t - 4;
    py = py < 0 ? 0 : (py > H - 1 ? H - 1 : py);
    s = fmaf(kb[t], tp[(long long)py << lw], s);
  }
  out[((long long)bc << (lw + lh)) + ((long long)y << lw) + x] += a * s;
}

// ---------------------------------------------------------------------------
// In-place AdaIN affine: x = (x-cm)/(cs+eps)*ss + sm  ==  a*x + d
// grid.y = b*C index
// ---------------------------------------------------------------------------
__global__ __launch_bounds__(TPB) void affine_kernel(float* __restrict__ x,
                                                     const float* __restrict__ mc,
                                                     const float* __restrict__ sc,
                                                     const float* __restrict__ ms,
                                                     const float* __restrict__ ss, int HW) {
  int bc = blockIdx.y;
  float a = ss[bc] / (sc[bc] + 1e-5f);
  float d = ms[bc] - mc[bc] * a;
  long long base = (long long)bc * HW;
  for (int i = blockIdx.x * TPB + threadIdx.x; i < HW; i += gridDim.x * TPB)
    x[base + i] = fmaf(x[base + i], a, d);
}

// ---------------------------------------------------------------------------
// Direct 3x3 conv, reflect pad 1, NCHW. 16x16 spatial tile per block,
// NCO output channels per thread. Weight addresses are wave-uniform.
// ---------------------------------------------------------------------------
template <int NCO, bool RELU>
__global__ __launch_bounds__(TPB) void conv3x3_kernel(const float* __restrict__ in,
                                                      const float* __restrict__ w,
                                                      const float* __restrict__ bias,
                                                      float* __restrict__ out,
                                                      int Cin, int Cout, int H, int W) {
  __shared__ float tile[18][18];
  const int tilesX = W >> 4;
  const int bt = blockIdx.x;
  const int tx0 = (bt % tilesX) << 4;
  const int ty0 = (bt / tilesX) << 4;
  const int co0 = blockIdx.y * NCO;
  const int b = blockIdx.z;
  const int tid = threadIdx.x;
  const int tx = tid & 15, ty = tid >> 4;
  const int x = tx0 + tx, y = ty0 + ty;

  float acc[NCO];
#pragma unroll
  for (int j = 0; j < NCO; ++j) acc[j] = 0.f;

  const long long inb = (long long)b * Cin * H * W;
  for (int ci = 0; ci < Cin; ++ci) {
    const float* ip = in + inb + (long long)ci * H * W;
    __syncthreads();
    for (int i = tid; i < 324; i += TPB) {
      int r = i / 18, cc = i - r * 18;
      int gy = ty0 - 1 + r;
      gy = gy < 0 ? -gy : (gy >= H ? 2 * H - 2 - gy : gy);
      int gx = tx0 - 1 + cc;
      gx = gx < 0 ? -gx : (gx >= W ? 2 * W - 2 - gx : gx);
      tile[r][cc] = ip[gy * W + gx];
    }
    __syncthreads();
    float v[9];
#pragma unroll
    for (int t = 0; t < 9; ++t) v[t] = tile[ty + t / 3][tx + t % 3];
    const float* wp = w + ((long long)co0 * Cin + ci) * 9;
#pragma unroll
    for (int j = 0; j < NCO; ++j) {
      const float* wj = wp + (long long)j * Cin * 9;
#pragma unroll
      for (int t = 0; t < 9; ++t) acc[j] = fmaf(wj[t], v[t], acc[j]);
    }
  }

  const long long ob = ((long long)b * Cout + co0) * H * W + (long long)y * W + x;
  const long long cs = (long long)H * W;
#pragma unroll
  for (int j = 0; j < NCO; ++j) {
    float r = acc[j] + bias[co0 + j];
    if (RELU) r = fmaxf(r, 0.f);
    out[ob + (long long)j * cs] = r;
  }
}

// ---------------------------------------------------------------------------
static inline void launch_conv(const float* in, const float* w, const float* bias,
                               float* out, int Cin, int Cout, int H, int W, bool relu,
                               hipStream_t s) {
  dim3 block(TPB);
  if (Cout % 16 == 0) {
    dim3 grid((W >> 4) * (H >> 4), Cout / 16, 4);
    if (relu)
      conv3x3_kernel<16, true><<<grid, block, 0, s>>>(in, w, bias, out, Cin, Cout, H, W);
    else
      conv3x3_kernel<16, false><<<grid, block, 0, s>>>(in, w, bias, out, Cin, Cout, H, W);
  } else {
    dim3 grid((W >> 4) * (H >> 4), 1, 4);
    if (relu)
      conv3x3_kernel<3, true><<<grid, block, 0, s>>>(in, w, bias, out, Cin, Cout, H, W);
    else
      conv3x3_kernel<3, false><<<grid, block, 0, s>>>(in, w, bias, out, Cin, Cout, H, W);
  }
}

extern "C" void kernel_launch(void* const* d_in, const int* in_sizes, int n_in,
                              void* d_out, int out_size, void* d_ws, size_t ws_size,
                              hipStream_t stream) {
  const float* x   = (const float*)d_in[0];
  const float* c34 = (const float*)d_in[1];
  const float* c22 = (const float*)d_in[2];
  const float* c12 = (const float*)d_in[3];
  const float* s34 = (const float*)d_in[4];
  const float* s31 = (const float*)d_in[5];
  const float* s22 = (const float*)d_in[6];
  const float* s21 = (const float*)d_in[7];
  const float* s12 = (const float*)d_in[8];
  const float* s11 = (const float*)d_in[9];
  const float* alphas = (const float*)d_in[10];
  const float* w41 = (const float*)d_in[11]; const float* b41 = (const float*)d_in[12];
  const float* w34 = (const float*)d_in[13]; const float* b34 = (const float*)d_in[14];
  const float* w33 = (const float*)d_in[15]; const float* b33 = (const float*)d_in[16];
  const float* w32 = (const float*)d_in[17]; const float* b32 = (const float*)d_in[18];
  const float* w31 = (const float*)d_in[19]; const float* b31 = (const float*)d_in[20];
  const float* w22 = (const float*)d_in[21]; const float* b22 = (const float*)d_in[22];
  const float* w21 = (const float*)d_in[23]; const float* b21 = (const float*)d_in[24];
  const float* w12 = (const float*)d_in[25]; const float* b12 = (const float*)d_in[26];
  const float* w11 = (const float*)d_in[27]; const float* b11 = (const float*)d_in[28];

  // workspace layout (floats)
  float* A  = (float*)d_ws;            // 16M floats (64 MB)
  float* Bb = A + 16777216;            // 16M floats (64 MB)
  float* P  = Bb + 16777216;           // 4M floats (16 MB) pool map
  float* mc = P + 4194304;             // content mean   [<=1024]
  float* sc = mc + 2048;               // content std
  float* ms = sc + 2048;               // style mean
  float* ss = ms + 2048;               // style std
  float* k1 = ss + 2048;               // 108 floats: [3][4][9]

  gauss1d_kernel<<<1, 128, 0, stream>>>(alphas, k1);

  // ---------------- level 4 -> 3 (64x64, 256ch) ----------------
  launch_conv(x, w41, b41, A, 512, 256, 32, 32, true, stream);
  {
    long long n = 4LL * 256 * 64 * 64;
    up2_kernel<<<(int)(n / TPB), TPB, 0, stream>>>(A, Bb, 6, 6, n);
  }
  stats_kernel<<<4 * 256, TPB, 0, stream>>>(c34, mc, sc, 64 * 64);
  stats_kernel<<<4 * 256, TPB, 0, stream>>>(s34, ms, ss, 64 * 64);
  {
    long long n = 4LL * 256 * 32 * 32;
    pool2_kernel<<<(int)(n / TPB), TPB, 0, stream>>>(c34, P, 5, 5, n);
  }
  {
    dim3 g((unsigned)((256LL * 64 * 64) / TPB), 1, 4);
    blurx_kernel<<<g, TPB, 0, stream>>>(c34, P, k1 + 72, A, 256, 6, 6);
    blury_add_kernel<<<g, TPB, 0, stream>>>(A, Bb, k1 + 72, sc, ss, 256, 6, 6);
  }
  launch_conv(Bb, w34, b34, A, 256, 256, 64, 64, true, stream);
  launch_conv(A, w33, b33, Bb, 256, 256, 64, 64, true, stream);
  launch_conv(Bb, w32, b32, A, 256, 256, 64, 64, true, stream);
  stats_kernel<<<4 * 256, TPB, 0, stream>>>(A, mc, sc, 64 * 64);
  stats_kernel<<<4 * 256, TPB, 0, stream>>>(s31, ms, ss, 64 * 64);
  {
    dim3 g(16, 4 * 256);
    affine_kernel<<<g, TPB, 0, stream>>>(A, mc, sc, ms, ss, 64 * 64);
  }
  launch_conv(A, w31, b31, Bb, 256, 128, 64, 64, true, stream);

  // ---------------- level 3 -> 2 (128x128, 128ch) ----------------
  {
    long long n = 4LL * 128 * 128 * 128;
    up2_kernel<<<(int)(n / TPB), TPB, 0, stream>>>(Bb, A, 7, 7, n);
  }
  stats_kernel<<<4 * 128, TPB, 0, stream>>>(c22, mc, sc, 128 * 128);
  stats_kernel<<<4 * 128, TPB, 0, stream>>>(s22, ms, ss, 128 * 128);
  {
    long long n = 4LL * 128 * 64 * 64;
    pool2_kernel<<<(int)(n / TPB), TPB, 0, stream>>>(c22, P, 6, 6, n);
  }
  {
    dim3 g((unsigned)((128LL * 128 * 128) / TPB), 1, 4);
    blurx_kernel<<<g, TPB, 0, stream>>>(c22, P, k1 + 36, Bb, 128, 7, 7);
    blury_add_kernel<<<g, TPB, 0, stream>>>(Bb, A, k1 + 36, sc, ss, 128, 7, 7);
  }
  launch_conv(A, w22, b22, Bb, 128, 128, 128, 128, true, stream);
  stats_kernel<<<4 * 128, TPB, 0, stream>>>(Bb, mc, sc, 128 * 128);
  stats_kernel<<<4 * 128, TPB, 0, stream>>>(s21, ms, ss, 128 * 128);
  {
    dim3 g(64, 4 * 128);
    affine_kernel<<<g, TPB, 0, stream>>>(Bb, mc, sc, ms, ss, 128 * 128);
  }
  launch_conv(Bb, w21, b21, A, 128, 64, 128, 128, true, stream);

  // ---------------- level 2 -> 1 (256x256, 64ch) ----------------
  {
    long long n = 4LL * 64 * 256 * 256;
    up2_kernel<<<(int)(n / TPB), TPB, 0, stream>>>(A, Bb, 8, 8, n);
  }
  stats_kernel<<<4 * 64, TPB, 0, stream>>>(c12, mc, sc, 256 * 256);
  stats_kernel<<<4 * 64, TPB, 0, stream>>>(s12, ms, ss, 256 * 256);
  {
    long long n = 4LL * 64 * 128 * 128;
    pool2_kernel<<<(int)(n / TPB), TPB, 0, stream>>>(c12, P, 7, 7, n);
  }
  {
    dim3 g((unsigned)((64LL * 256 * 256) / TPB), 1, 4);
    blurx_kernel<<<g, TPB, 0, stream>>>(c12, P, k1 + 0, A, 64, 8, 8);
    blury_add_kernel<<<g, TPB, 0, stream>>>(A, Bb, k1 + 0, sc, ss, 64, 8, 8);
  }
  launch_conv(Bb, w12, b12, A, 64, 64, 256, 256, true, stream);
  stats_kernel<<<4 * 64, TPB, 0, stream>>>(A, mc, sc, 256 * 256);
  stats_kernel<<<4 * 64, TPB, 0, stream>>>(s11, ms, ss, 256 * 256);
  {
    dim3 g(256, 4 * 64);
    affine_kernel<<<g, TPB, 0, stream>>>(A, mc, sc, ms, ss, 256 * 256);
  }
  launch_conv(A, w11, b11, (float*)d_out, 64, 3, 256, 256, false, stream);
}

// Round 2
// 3797.663 us; speedup vs baseline: 1.7915x; 1.7915x over previous
//
#include <hip/hip_runtime.h>
#include <math.h>

#define TPB 256

// ---------------------------------------------------------------------------
// Per-sample separable 1D gaussian kernels (normalized), all 3 levels at once.
// k1d layout: [lvl][b][9], lvl = column index into alphas (0->256^2, 1->128^2, 2->64^2)
// ---------------------------------------------------------------------------
__global__ __launch_bounds__(128) void gauss1d_kernel(const float* __restrict__ alphas,
                                                      float* __restrict__ k1d) {
  int t = threadIdx.x;
  if (t >= 108) return;
  int lvl = t / 36;
  int rem = t - lvl * 36;
  int b = rem / 9;
  int j = rem - b * 9;
  float alpha = alphas[b * 3 + lvl];
  float k = floorf(floorf(alpha * 8.f) * 0.5f) * 2.f + 1.f;
  float r = (k - 1.f) * 0.5f;
  float sum = 0.f, val = 0.f;
  for (int u = 0; u < 9; ++u) {
    float d = (float)(u - 4);
    float g = expf(-(d * d) / 512.f);   // 2*sigma^2 = 512
    if (fabsf(d) > r) g = 0.f;
    if (u == j) val = g;
    sum += g;
  }
  k1d[(lvl * 4 + b) * 9 + j] = val / sum;
}

// ---------------------------------------------------------------------------
// Per-(b,c) mean + unbiased std over HW. One block per (b,c).
// ---------------------------------------------------------------------------
__global__ __launch_bounds__(TPB) void stats_kernel(const float* __restrict__ x,
                                                    float* __restrict__ mean,
                                                    float* __restrict__ stdv, int HW) {
  long long base = (long long)blockIdx.x * HW;
  float s = 0.f, q = 0.f;
  for (int i = threadIdx.x; i < HW; i += TPB) {
    float v = x[base + i];
    s += v;
    q = fmaf(v, v, q);
  }
#pragma unroll
  for (int off = 32; off > 0; off >>= 1) {
    s += __shfl_down(s, off, 64);
    q += __shfl_down(q, off, 64);
  }
  __shared__ float sm[8];
  int w = threadIdx.x >> 6, lane = threadIdx.x & 63;
  if (lane == 0) { sm[w * 2] = s; sm[w * 2 + 1] = q; }
  __syncthreads();
  if (threadIdx.x == 0) {
    float S = sm[0] + sm[2] + sm[4] + sm[6];
    float Q = sm[1] + sm[3] + sm[5] + sm[7];
    float m = S / (float)HW;
    float var = (Q - S * m) / (float)(HW - 1);
    mean[blockIdx.x] = m;
    stdv[blockIdx.x] = sqrtf(fmaxf(var, 0.f));
  }
}

// ---------------------------------------------------------------------------
// 2x2 mean pool: dst has half resolution. n = total dst elements.
// ---------------------------------------------------------------------------
__global__ __launch_bounds__(TPB) void pool2_kernel(const float* __restrict__ src,
                                                    float* __restrict__ dst,
                                                    int lwh, int lhh, long long n) {
  long long i = (long long)blockIdx.x * TPB + threadIdx.x;
  if (i >= n) return;
  int Wh = 1 << lwh, Hh = 1 << lhh;
  int px = (int)(i & (Wh - 1));
  int py = (int)((i >> lwh) & (Hh - 1));
  long long bc = i >> (lwh + lhh);
  const float* sp = src + (bc << (lwh + lhh + 2)) + (long long)(py * 2) * (Wh * 2) + px * 2;
  dst[i] = 0.25f * (sp[0] + sp[1] + sp[Wh * 2] + sp[Wh * 2 + 1]);
}

// ---------------------------------------------------------------------------
// Nearest 2x upsample. lw/lh are log2 of OUTPUT dims. n = total dst elements.
// ---------------------------------------------------------------------------
__global__ __launch_bounds__(TPB) void up2_kernel(const float* __restrict__ src,
                                                  float* __restrict__ dst,
                                                  int lw, int lh, long long n) {
  long long i = (long long)blockIdx.x * TPB + threadIdx.x;
  if (i >= n) return;
  int Wo = 1 << lw, Ho = 1 << lh;
  int x = (int)(i & (Wo - 1));
  int y = (int)((i >> lw) & (Ho - 1));
  long long bc = i >> (lw + lh);
  dst[i] = src[(bc << (lw + lh - 2)) + (long long)(y >> 1) * (Wo >> 1) + (x >> 1)];
}

// ---------------------------------------------------------------------------
// blurX: dst = 1D conv over x (replicate pad) of hh(c) where
//        hh(y,x) = c[y][x] - pool[y>>1][x>>1]  (pool precomputed)
// ---------------------------------------------------------------------------
__global__ __launch_bounds__(TPB) void blurx_kernel(const float* __restrict__ src,
                                                    const float* __restrict__ pmap,
                                                    const float* __restrict__ k1d,
                                                    float* __restrict__ dst,
                                                    int C, int lw, int lh) {
  int b = blockIdx.z;
  float kb[9];
#pragma unroll
  for (int t = 0; t < 9; ++t) kb[t] = k1d[b * 9 + t];
  int W = 1 << lw, H = 1 << lh;
  (void)H;
  long long i = (long long)blockIdx.x * TPB + threadIdx.x;
  long long nper = (long long)C << (lw + lh);
  if (i >= nper) return;
  int x = (int)(i & (W - 1));
  long long rest = i >> lw;
  int y = (int)(rest & ((1 << lh) - 1));
  int c = (int)(rest >> lh);
  long long bc = (long long)b * C + c;
  const float* sp = src + (bc << (lw + lh)) + ((long long)y << lw);
  const float* pp = pmap + (bc << (lw + lh - 2)) + ((long long)(y >> 1) << (lw - 1));
  float s = 0.f;
#pragma unroll
  for (int t = 0; t < 9; ++t) {
    int px = x + t - 4;
    px = px < 0 ? 0 : (px > W - 1 ? W - 1 : px);
    s = fmaf(kb[t], sp[px] - pp[px >> 1], s);
  }
  dst[(bc << (lw + lh)) + ((long long)y << lw) + x] = s;
}

// ---------------------------------------------------------------------------
// blurY + scale + add:  out += (std_s/(std_c+eps)) * 1D conv over y of tmp
// ---------------------------------------------------------------------------
__global__ __launch_bounds__(TPB) void blury_add_kernel(const float* __restrict__ tmp,
                                                        float* __restrict__ out,
                                                        const float* __restrict__ k1d,
                                                        const float* __restrict__ stdc,
                                                        const float* __restrict__ stds,
                                                        int C, int lw, int lh) {
  int b = blockIdx.z;
  float kb[9];
#pragma unroll
  for (int t = 0; t < 9; ++t) kb[t] = k1d[b * 9 + t];
  int W = 1 << lw, H = 1 << lh;
  long long i = (long long)blockIdx.x * TPB + threadIdx.x;
  long long nper = (long long)C << (lw + lh);
  if (i >= nper) return;
  int x = (int)(i & (W - 1));
  long long rest = i >> lw;
  int y = (int)(rest & (H - 1));
  int c = (int)(rest >> lh);
  int bc = b * C + c;
  float a = stds[bc] / (stdc[bc] + 1e-5f);
  const float* tp = tmp + ((long long)bc << (lw + lh)) + x;
  float s = 0.f;
#pragma unroll
  for (int t = 0; t < 9; ++t) {
    int py = y + t - 4;
    py = py < 0 ? 0 : (py > H - 1 ? H - 1 : py);
    s = fmaf(kb[t], tp[(long long)py << lw], s);
  }
  out[((long long)bc << (lw + lh)) + ((long long)y << lw) + x] += a * s;
}

// ---------------------------------------------------------------------------
// In-place AdaIN affine: x = (x-cm)/(cs+eps)*ss + sm  ==  a*x + d
// ---------------------------------------------------------------------------
__global__ __launch_bounds__(TPB) void affine_kernel(float* __restrict__ x,
                                                     const float* __restrict__ mc,
                                                     const float* __restrict__ sc,
                                                     const float* __restrict__ ms,
                                                     const float* __restrict__ ss, int HW) {
  int bc = blockIdx.y;
  float a = ss[bc] / (sc[bc] + 1e-5f);
  float d = ms[bc] - mc[bc] * a;
  long long base = (long long)bc * HW;
  for (int i = blockIdx.x * TPB + threadIdx.x; i < HW; i += gridDim.x * TPB)
    x[base + i] = fmaf(x[base + i], a, d);
}

// ---------------------------------------------------------------------------
// bias + relu (epilogue for split-K atomic convs)
// ---------------------------------------------------------------------------
__global__ __launch_bounds__(TPB) void bias_relu_kernel(float* __restrict__ x,
                                                        const float* __restrict__ bias,
                                                        int HW, int C, long long n) {
  long long i = (long long)blockIdx.x * TPB + threadIdx.x;
  if (i >= n) return;
  int c = (int)((i / HW) % C);
  x[i] = fmaxf(x[i] + bias[c], 0.f);
}

// ---------------------------------------------------------------------------
// Register-tiled implicit-GEMM 3x3 conv, reflect pad 1, NCHW fp32.
// Block: 32 co x 256 px (16x16 tile). Thread: 4 co x 8 px.
// K chunked by 8 input channels; input tile + weights staged in LDS.
// ATOMIC: split-K accumulate (bias applied later); else bias(+relu) store.
// ---------------------------------------------------------------------------
template <bool RELU, bool ATOMIC>
__global__ __launch_bounds__(TPB) void conv_gemm_kernel(
    const float* __restrict__ in, const float* __restrict__ wgt,
    const float* __restrict__ bias, float* __restrict__ out,
    int Cin, int Cout, int H, int W, int ciPer, int ksplit) {
  __shared__ __align__(16) float tIn[8][18][20];   // [ci][iy][ix], ix pad->20
  __shared__ __align__(16) float tW[8][9][32];     // [ci][t][co_local]

  const int tid = threadIdx.x;
  const int tilesX = W >> 4;
  const int tx0 = (blockIdx.x % tilesX) << 4;
  const int ty0 = (blockIdx.x / tilesX) << 4;
  const int co0 = blockIdx.y << 5;
  const int b = blockIdx.z / ksplit;
  const int kz = blockIdx.z % ksplit;
  const int ci0 = kz * ciPer;

  const int cg = tid & 7;          // co group: 8 groups of 4 co
  const int pg = tid >> 3;         // px group: 32 groups of 8 px
  const int y = pg >> 1;           // 0..15
  const int xh = (pg & 1) << 3;    // 0 or 8
  const int cg4 = cg << 2;

  float acc[4][8];
#pragma unroll
  for (int j = 0; j < 4; ++j)
#pragma unroll
    for (int p = 0; p < 8; ++p) acc[j][p] = 0.f;

  const long long inB = (long long)b * Cin * H * W;

  for (int cc = 0; cc < ciPer; cc += 8) {
    const int cib = ci0 + cc;
    __syncthreads();
    // stage input 8 x 18 x 18 (reflect pad 1)
    for (int i = tid; i < 8 * 324; i += TPB) {
      int ci = i / 324;
      int rem = i - ci * 324;
      int iy = rem / 18;
      int ix = rem - iy * 18;
      int gy = ty0 - 1 + iy;
      gy = gy < 0 ? -gy : (gy >= H ? 2 * H - 2 - gy : gy);
      int gx = tx0 - 1 + ix;
      gx = gx < 0 ? -gx : (gx >= W ? 2 * W - 2 - gx : gx);
      tIn[ci][iy][ix] = in[inB + (long long)(cib + ci) * H * W + (long long)gy * W + gx];
    }
    // stage weights 32co x 8ci x 9
    for (int i = tid; i < 8 * 9 * 32; i += TPB) {
      int co_l = i / 72;
      int rem = i - co_l * 72;
      int ci = rem / 9;
      int t = rem - ci * 9;
      tW[ci][t][co_l] = wgt[((long long)(co0 + co_l) * Cin + cib + ci) * 9 + t];
    }
    __syncthreads();

#pragma unroll 2
    for (int ci = 0; ci < 8; ++ci) {
#pragma unroll
      for (int r = 0; r < 3; ++r) {
        const float* row = &tIn[ci][y + r][xh];
        float4 f0 = *(const float4*)row;
        float4 f1 = *(const float4*)(row + 4);
        float2 f2 = *(const float2*)(row + 8);
        float f[10] = {f0.x, f0.y, f0.z, f0.w, f1.x, f1.y, f1.z, f1.w, f2.x, f2.y};
#pragma unroll
        for (int c = 0; c < 3; ++c) {
          float4 wv = *(const float4*)&tW[ci][r * 3 + c][cg4];
          float wa[4] = {wv.x, wv.y, wv.z, wv.w};
#pragma unroll
          for (int j = 0; j < 4; ++j)
#pragma unroll
            for (int p = 0; p < 8; ++p)
              acc[j][p] = fmaf(wa[j], f[p + c], acc[j][p]);
        }
      }
    }
  }

  const long long HWl = (long long)H * W;
#pragma unroll
  for (int j = 0; j < 4; ++j) {
    const int co = co0 + cg4 + j;
    float* op = out + ((long long)b * Cout + co) * HWl + (long long)(ty0 + y) * W + tx0 + xh;
    if (ATOMIC) {
#pragma unroll
      for (int p = 0; p < 8; ++p) atomicAdd(&op[p], acc[j][p]);
    } else {
      const float bv = bias[co];
      float o[8];
#pragma unroll
      for (int p = 0; p < 8; ++p) {
        o[p] = acc[j][p] + bv;
        if (RELU) o[p] = fmaxf(o[p], 0.f);
      }
      *(float4*)op = make_float4(o[0], o[1], o[2], o[3]);
      *(float4*)(op + 4) = make_float4(o[4], o[5], o[6], o[7]);
    }
  }
}

// ---------------------------------------------------------------------------
// Small final conv: Cout=3, per-thread 1 px, weights via wave-uniform s_loads.
// ---------------------------------------------------------------------------
__global__ __launch_bounds__(TPB) void conv3x3_c3_kernel(
    const float* __restrict__ in, const float* __restrict__ wgt,
    const float* __restrict__ bias, float* __restrict__ out,
    int Cin, int H, int W) {
  __shared__ __align__(16) float tIn[8][18][20];
  const int tid = threadIdx.x;
  const int tilesX = W >> 4;
  const int tx0 = (blockIdx.x % tilesX) << 4;
  const int ty0 = (blockIdx.x / tilesX) << 4;
  const int b = blockIdx.z;
  const int tx = tid & 15, ty = tid >> 4;

  float acc[3] = {0.f, 0.f, 0.f};
  const long long inB = (long long)b * Cin * H * W;

  for (int cc = 0; cc < Cin; cc += 8) {
    __syncthreads();
    for (int i = tid; i < 8 * 324; i += TPB) {
      int ci = i / 324;
      int rem = i - ci * 324;
      int iy = rem / 18;
      int ix = rem - iy * 18;
      int gy = ty0 - 1 + iy;
      gy = gy < 0 ? -gy : (gy >= H ? 2 * H - 2 - gy : gy);
      int gx = tx0 - 1 + ix;
      gx = gx < 0 ? -gx : (gx >= W ? 2 * W - 2 - gx : gx);
      tIn[ci][iy][ix] = in[inB + (long long)(cc + ci) * H * W + (long long)gy * W + gx];
    }
    __syncthreads();
#pragma unroll 2
    for (int ci = 0; ci < 8; ++ci) {
#pragma unroll
      for (int r = 0; r < 3; ++r)
#pragma unroll
        for (int c = 0; c < 3; ++c) {
          float v = tIn[ci][ty + r][tx + c];
          int t = r * 3 + c;
          acc[0] = fmaf(wgt[((long long)(0 * Cin) + cc + ci) * 9 + t], v, acc[0]);
          acc[1] = fmaf(wgt[((long long)(1 * Cin) + cc + ci) * 9 + t], v, acc[1]);
          acc[2] = fmaf(wgt[((long long)(2 * Cin) + cc + ci) * 9 + t], v, acc[2]);
        }
    }
  }
  const long long HWl = (long long)H * W;
#pragma unroll
  for (int co = 0; co < 3; ++co)
    out[((long long)b * 3 + co) * HWl + (long long)(ty0 + ty) * W + tx0 + tx] =
        acc[co] + bias[co];
}

// ---------------------------------------------------------------------------
static inline void launch_conv(const float* in, const float* w, const float* bias,
                               float* out, int Cin, int Cout, int H, int W,
                               int ksplit, hipStream_t s) {
  dim3 grid((W >> 4) * (H >> 4), Cout >> 5, 4 * ksplit);
  int ciPer = Cin / ksplit;
  if (ksplit > 1)
    conv_gemm_kernel<false, true><<<grid, TPB, 0, s>>>(in, w, bias, out, Cin, Cout, H, W, ciPer, ksplit);
  else
    conv_gemm_kernel<true, false><<<grid, TPB, 0, s>>>(in, w, bias, out, Cin, Cout, H, W, ciPer, 1);
}

extern "C" void kernel_launch(void* const* d_in, const int* in_sizes, int n_in,
                              void* d_out, int out_size, void* d_ws, size_t ws_size,
                              hipStream_t stream) {
  const float* x   = (const float*)d_in[0];
  const float* c34 = (const float*)d_in[1];
  const float* c22 = (const float*)d_in[2];
  const float* c12 = (const float*)d_in[3];
  const float* s34 = (const float*)d_in[4];
  const float* s31 = (const float*)d_in[5];
  const float* s22 = (const float*)d_in[6];
  const float* s21 = (const float*)d_in[7];
  const float* s12 = (const float*)d_in[8];
  const float* s11 = (const float*)d_in[9];
  const float* alphas = (const float*)d_in[10];
  const float* w41 = (const float*)d_in[11]; const float* b41 = (const float*)d_in[12];
  const float* w34 = (const float*)d_in[13]; const float* b34 = (const float*)d_in[14];
  const float* w33 = (const float*)d_in[15]; const float* b33 = (const float*)d_in[16];
  const float* w32 = (const float*)d_in[17]; const float* b32 = (const float*)d_in[18];
  const float* w31 = (const float*)d_in[19]; const float* b31 = (const float*)d_in[20];
  const float* w22 = (const float*)d_in[21]; const float* b22 = (const float*)d_in[22];
  const float* w21 = (const float*)d_in[23]; const float* b21 = (const float*)d_in[24];
  const float* w12 = (const float*)d_in[25]; const float* b12 = (const float*)d_in[26];
  const float* w11 = (const float*)d_in[27]; const float* b11 = (const float*)d_in[28];

  // workspace layout (floats)
  float* A  = (float*)d_ws;            // 16M floats (64 MB)
  float* Bb = A + 16777216;            // 16M floats (64 MB)
  float* P  = Bb + 16777216;           // 4M floats (16 MB) pool map
  float* mc = P + 4194304;
  float* sc = mc + 2048;
  float* ms = sc + 2048;
  float* ss = ms + 2048;
  float* k1 = ss + 2048;               // 108 floats: [3][4][9]

  gauss1d_kernel<<<1, 128, 0, stream>>>(alphas, k1);

  // ---------------- level 4 -> 3 (64x64, 256ch) ----------------
  hipMemsetAsync(A, 0, 4LL * 256 * 32 * 32 * 4, stream);
  launch_conv(x, w41, b41, A, 512, 256, 32, 32, 4, stream);
  {
    long long n = 4LL * 256 * 1024;
    bias_relu_kernel<<<(int)(n / TPB), TPB, 0, stream>>>(A, b41, 1024, 256, n);
  }
  {
    long long n = 4LL * 256 * 64 * 64;
    up2_kernel<<<(int)(n / TPB), TPB, 0, stream>>>(A, Bb, 6, 6, n);
  }
  stats_kernel<<<4 * 256, TPB, 0, stream>>>(c34, mc, sc, 64 * 64);
  stats_kernel<<<4 * 256, TPB, 0, stream>>>(s34, ms, ss, 64 * 64);
  {
    long long n = 4LL * 256 * 32 * 32;
    pool2_kernel<<<(int)(n / TPB), TPB, 0, stream>>>(c34, P, 5, 5, n);
  }
  {
    dim3 g((unsigned)((256LL * 64 * 64) / TPB), 1, 4);
    blurx_kernel<<<g, TPB, 0, stream>>>(c34, P, k1 + 72, A, 256, 6, 6);
    blury_add_kernel<<<g, TPB, 0, stream>>>(A, Bb, k1 + 72, sc, ss, 256, 6, 6);
  }
  launch_conv(Bb, w34, b34, A, 256, 256, 64, 64, 1, stream);
  launch_conv(A, w33, b33, Bb, 256, 256, 64, 64, 1, stream);
  launch_conv(Bb, w32, b32, A, 256, 256, 64, 64, 1, stream);
  stats_kernel<<<4 * 256, TPB, 0, stream>>>(A, mc, sc, 64 * 64);
  stats_kernel<<<4 * 256, TPB, 0, stream>>>(s31, ms, ss, 64 * 64);
  {
    dim3 g(16, 4 * 256);
    affine_kernel<<<g, TPB, 0, stream>>>(A, mc, sc, ms, ss, 64 * 64);
  }
  hipMemsetAsync(Bb, 0, 4LL * 128 * 64 * 64 * 4, stream);
  launch_conv(A, w31, b31, Bb, 256, 128, 64, 64, 2, stream);
  {
    long long n = 4LL * 128 * 4096;
    bias_relu_kernel<<<(int)(n / TPB), TPB, 0, stream>>>(Bb, b31, 4096, 128, n);
  }

  // ---------------- level 3 -> 2 (128x128, 128ch) ----------------
  {
    long long n = 4LL * 128 * 128 * 128;
    up2_kernel<<<(int)(n / TPB), TPB, 0, stream>>>(Bb, A, 7, 7, n);
  }
  stats_kernel<<<4 * 128, TPB, 0, stream>>>(c22, mc, sc, 128 * 128);
  stats_kernel<<<4 * 128, TPB, 0, stream>>>(s22, ms, ss, 128 * 128);
  {
    long long n = 4LL * 128 * 64 * 64;
    pool2_kernel<<<(int)(n / TPB), TPB, 0, stream>>>(c22, P, 6, 6, n);
  }
  {
    dim3 g((unsigned)((128LL * 128 * 128) / TPB), 1, 4);
    blurx_kernel<<<g, TPB, 0, stream>>>(c22, P, k1 + 36, Bb, 128, 7, 7);
    blury_add_kernel<<<g, TPB, 0, stream>>>(Bb, A, k1 + 36, sc, ss, 128, 7, 7);
  }
  launch_conv(A, w22, b22, Bb, 128, 128, 128, 128, 1, stream);
  stats_kernel<<<4 * 128, TPB, 0, stream>>>(Bb, mc, sc, 128 * 128);
  stats_kernel<<<4 * 128, TPB, 0, stream>>>(s21, ms, ss, 128 * 128);
  {
    dim3 g(64, 4 * 128);
    affine_kernel<<<g, TPB, 0, stream>>>(Bb, mc, sc, ms, ss, 128 * 128);
  }
  launch_conv(Bb, w21, b21, A, 128, 64, 128, 128, 1, stream);

  // ---------------- level 2 -> 1 (256x256, 64ch) ----------------
  {
    long long n = 4LL * 64 * 256 * 256;
    up2_kernel<<<(int)(n / TPB), TPB, 0, stream>>>(A, Bb, 8, 8, n);
  }
  stats_kernel<<<4 * 64, TPB, 0, stream>>>(c12, mc, sc, 256 * 256);
  stats_kernel<<<4 * 64, TPB, 0, stream>>>(s12, ms, ss, 256 * 256);
  {
    long long n = 4LL * 64 * 128 * 128;
    pool2_kernel<<<(int)(n / TPB), TPB, 0, stream>>>(c12, P, 7, 7, n);
  }
  {
    dim3 g((unsigned)((64LL * 256 * 256) / TPB), 1, 4);
    blurx_kernel<<<g, TPB, 0, stream>>>(c12, P, k1 + 0, A, 64, 8, 8);
    blury_add_kernel<<<g, TPB, 0, stream>>>(A, Bb, k1 + 0, sc, ss, 64, 8, 8);
  }
  launch_conv(Bb, w12, b12, A, 64, 64, 256, 256, 1, stream);
  stats_kernel<<<4 * 64, TPB, 0, stream>>>(A, mc, sc, 256 * 256);
  stats_kernel<<<4 * 64, TPB, 0, stream>>>(s11, ms, ss, 256 * 256);
  {
    dim3 g(256, 4 * 64);
    affine_kernel<<<g, TPB, 0, stream>>>(A, mc, sc, ms, ss, 256 * 256);
  }
  conv3x3_c3_kernel<<<dim3(256, 1, 4), TPB, 0, stream>>>(A, w11, b11, (float*)d_out,
                                                         64, 256, 256);
}